// Round 10
// baseline (262.024 us; speedup 1.0000x reference)
//
#include <hip/hip_runtime.h>
#include <hip/hip_bf16.h>
#include <math.h>

#define CIN 256
#define CH  64
#define CO  47
#define NPAD 102400   // n=100000 rounded up
#define ELLW 48       // ELL width; deg ~ Poisson(16); overflow guarded
#define EDGE_CHUNK 4096
#define SUBCAP 26624  // per-bin capacity: E/64=25000 + ~10-sigma slack

typedef __attribute__((ext_vector_type(8))) short bf16x8;
typedef __attribute__((ext_vector_type(4))) short short4v;
typedef __attribute__((ext_vector_type(4))) float f32x4;

__device__ inline short bf16s(float f) {
    union { __hip_bfloat16 h; short s; } u;
    u.h = __float2bfloat16(f);
    return u.s;
}

__device__ inline float bf2f(short u) {
    union { unsigned int i; float f; } v;
    v.i = ((unsigned int)(unsigned short)u) << 16;
    return v.f;
}

// ---------------- two-level binned ELL build ----------------
// r9 lesson: 8-way slicing alone leaves WRITE_SIZE at 64MB because a node's
// ~16 slot-writes are spread across the WHOLE kernel -- partial ELL lines
// can't survive in L2 that long. Fix: 64 bins (8 XCD-slices x 8 sub-bins).
// Phase 2 walks its slice's sub-bins IN ORDER, so at any moment one slice
// hammers a ~300KB ELL sub-region: lines complete within a short epoch and
// evict once. bin id recomputed from d (no per-element search).

__global__ void zero_i32(int* __restrict__ p, int n) {
    int i = blockIdx.x * blockDim.x + threadIdx.x;
    if (i < n) p[i] = 0;
}

__global__ __launch_bounds__(256) void bin_edges(const int* __restrict__ src,
                                                 const int* __restrict__ dst,
                                                 int* __restrict__ bin_cnt,
                                                 long long* __restrict__ bins,
                                                 int E, float inv64) {
    __shared__ int2 stage[EDGE_CHUNK];   // 32 KB
    __shared__ int lcnt[64], lbase[65], lcur[64], gbase[64];
    int t = threadIdx.x;
    int base = blockIdx.x * EDGE_CHUNK;
    int end = min(base + EDGE_CHUNK, E);
    if (t < 64) lcnt[t] = 0;
    __syncthreads();

    // pass A: per-bin counts (bin via float mul; boundary rounding only moves
    // a node between adjacent bins -> locality detail, never correctness)
    for (int i = base + t; i < end; i += 256) {
        int d = __builtin_nontemporal_load(&dst[i]);
        int b = min(63, (int)((float)d * inv64));
        atomicAdd(&lcnt[b], 1);
    }
    __syncthreads();
    if (t == 0) {
        int s = 0;
        #pragma unroll
        for (int k = 0; k < 64; ++k) { lbase[k] = s; s += lcnt[k]; }
        lbase[64] = s;
    }
    __syncthreads();
    if (t < 64) lcur[t] = lbase[t];
    __syncthreads();

    // pass B: stage grouped by bin
    for (int i = base + t; i < end; i += 256) {
        int d = __builtin_nontemporal_load(&dst[i]);
        int s = __builtin_nontemporal_load(&src[i]);
        int b = min(63, (int)((float)d * inv64));
        int pos = atomicAdd(&lcur[b], 1);
        stage[pos] = make_int2(d, s);
    }
    __syncthreads();

    // reserve global space: one atomic per bin per block (counters 64B apart)
    if (t < 64) gbase[t] = atomicAdd(&bin_cnt[t << 4], lcnt[t]);
    __syncthreads();

    // pass C: copy out, coalesced within bin segments (bin recomputed from d)
    int total = end - base;
    for (int j = t; j < total; j += 256) {
        int2 e = stage[j];
        int b = min(63, (int)((float)e.x * inv64));
        int pos = gbase[b] + (j - lbase[b]);
        if (pos < SUBCAP)
            bins[(size_t)b * SUBCAP + pos] =
                ((long long)(unsigned)e.y << 32) | (unsigned)e.x;
    }
}

__global__ __launch_bounds__(256) void fill_ell2(const long long* __restrict__ bins,
                                                 const int* __restrict__ bin_cnt,
                                                 int* __restrict__ cnt,
                                                 int* __restrict__ ell) {
    int slice = blockIdx.x & 7;          // round-robin blockIdx -> XCD
    int blk   = blockIdx.x >> 3;
    int nblk  = gridDim.x >> 3;
    for (int sb = 0; sb < 8; ++sb) {     // sub-bins in order: temporal clustering
        int bin = slice * 8 + sb;
        int c_b = min(bin_cnt[bin << 4], SUBCAP);
        const long long* b = bins + (size_t)bin * SUBCAP;
        for (int i = blk * 256 + threadIdx.x; i < c_b; i += nblk * 256) {
            long long e = __builtin_nontemporal_load(&b[i]);
            int d = (int)(e & 0xffffffffLL);
            int s = (int)(e >> 32);
            int slot = atomicAdd(&cnt[d], 1);
            if (slot < ELLW) ell[(size_t)d * ELLW + slot] = s;
        }
    }
}

__global__ void dinv_k(const int* __restrict__ cnt, float* __restrict__ dinv, int n) {
    int i = blockIdx.x * blockDim.x + threadIdx.x;
    if (i < n) dinv[i] = rsqrtf(1.0f + (float)cnt[i]);  // self-loop included
}

// ---------------- layer-1 GEMM (MFMA): h1p = dinv * (x @ W1^T)  (bf16 out) ----------------
// Premultiplied by dinv[row] so aggregation is pure adds. r6-proven LDS staging.

__global__ __launch_bounds__(256) void gemm1_mfma(const float* __restrict__ x,
                                                  const float* __restrict__ W1,
                                                  const float* __restrict__ dinv,
                                                  unsigned short* __restrict__ h1p, int n) {
    __shared__ short w1s[CH * CIN];  // [64][256] bf16, swizzled rows (32 KB)
    int t = threadIdx.x;
    int row0 = blockIdx.x * 64;

    for (int i = t; i < CH * (CIN / 4); i += 256) {
        int row = i >> 6;
        int f4  = i & 63;
        float4 v = *(const float4*)(W1 + (size_t)row * CIN + f4 * 4);
        short4v b;
        b[0] = bf16s(v.x); b[1] = bf16s(v.y); b[2] = bf16s(v.z); b[3] = bf16s(v.w);
        int kbyte = f4 * 8;
        *(short4v*)((char*)w1s + (row << 9) + (kbyte ^ ((row & 7) << 4))) = b;
    }
    __syncthreads();

    int l  = t & 63;
    int w  = t >> 6;
    int g  = l >> 4;
    int lr = l & 15;

    bf16x8 bfr[4][8];
    #pragma unroll
    for (int cb = 0; cb < 4; ++cb) {
        int col = cb * 16 + lr;
        #pragma unroll
        for (int kk = 0; kk < 8; ++kk) {
            int kbyte = (kk * 32 + g * 8) * 2;
            bfr[cb][kk] = *(const bf16x8*)((char*)w1s + (col << 9) + (kbyte ^ ((col & 7) << 4)));
        }
    }

    f32x4 acc[4];
    #pragma unroll
    for (int cb = 0; cb < 4; ++cb) acc[cb] = (f32x4){0.f, 0.f, 0.f, 0.f};

    int arow = row0 + w * 16 + lr;
    if (arow >= n) arow = n - 1;     // clamp: loads stay in-bounds; store guarded
    const float* ga = x + (size_t)arow * CIN + g * 8;

    #pragma unroll
    for (int kk = 0; kk < 8; ++kk) {
        float4 a0 = *(const float4*)(ga + kk * 32);
        float4 a1 = *(const float4*)(ga + kk * 32 + 4);
        bf16x8 af;
        af[0] = bf16s(a0.x); af[1] = bf16s(a0.y); af[2] = bf16s(a0.z); af[3] = bf16s(a0.w);
        af[4] = bf16s(a1.x); af[5] = bf16s(a1.y); af[6] = bf16s(a1.z); af[7] = bf16s(a1.w);
        #pragma unroll
        for (int cb = 0; cb < 4; ++cb)
            acc[cb] = __builtin_amdgcn_mfma_f32_16x16x32_bf16(af, bfr[cb][kk], acc[cb], 0, 0, 0);
    }

    float dv[4];
    #pragma unroll
    for (int r = 0; r < 4; ++r) {
        int drow = row0 + w * 16 + g * 4 + r;
        dv[r] = dinv[drow < n ? drow : (n - 1)];
    }
    #pragma unroll
    for (int cb = 0; cb < 4; ++cb) {
        #pragma unroll
        for (int r = 0; r < 4; ++r) {
            int drow = row0 + w * 16 + g * 4 + r;   // C/D: col=lane&15, row=(lane>>4)*4+reg
            if (drow < n)
                h1p[(size_t)drow * CH + cb * 16 + lr] = (unsigned short)bf16s(acc[cb][r] * dv[r]);
        }
    }
}

// ---------------- gather aggregation over ELL: pure adds, 8-edge groups, x2 unroll ----
// MODE 0 (layer 1): out = bf16( di * relu(di*acc + b1) )   [premult for layer 2]
// MODE 1 (layer 2): out = bf16( di * acc )                  [input to final gemm]

template <int MODE>
__global__ __launch_bounds__(256) void aggregate(const unsigned short* __restrict__ h,
                                                 const float* __restrict__ dinv,
                                                 const int* __restrict__ ell,
                                                 const int* __restrict__ cnt,
                                                 const float* __restrict__ bias,
                                                 unsigned short* __restrict__ outp, int n) {
    int lane = threadIdx.x & 63;
    int node = blockIdx.x * (blockDim.x >> 6) + (threadIdx.x >> 6);
    if (node >= n) return;
    int g = lane >> 3;
    int r = lane & 7;

    float di = dinv[node];
    int deg = min(cnt[node], ELLW);          // clamp: overflow slots were dropped
    const int* row = ell + (size_t)node * ELLW;

    float acc[8];
    #pragma unroll
    for (int i = 0; i < 8; ++i) acc[i] = 0.f;

    if (g == 0) {                            // self term: h_p[node], weight 1
        bf16x8 v = *(const bf16x8*)(h + (size_t)node * CH + r * 8);
        #pragma unroll
        for (int i = 0; i < 8; ++i) acc[i] += bf2f(v[i]);
    }

    int j = g;
    for (; j + 8 < deg; j += 16) {           // x2 unroll: 2 rows in flight per lane
        int s0 = row[j];
        int s1 = row[j + 8];
        bf16x8 v0 = *(const bf16x8*)(h + (size_t)s0 * CH + r * 8);
        bf16x8 v1 = *(const bf16x8*)(h + (size_t)s1 * CH + r * 8);
        #pragma unroll
        for (int i = 0; i < 8; ++i) acc[i] += bf2f(v0[i]) + bf2f(v1[i]);
    }
    if (j < deg) {
        int s = row[j];
        bf16x8 v = *(const bf16x8*)(h + (size_t)s * CH + r * 8);
        #pragma unroll
        for (int i = 0; i < 8; ++i) acc[i] += bf2f(v[i]);
    }

    #pragma unroll
    for (int m = 8; m <= 32; m <<= 1) {
        #pragma unroll
        for (int i = 0; i < 8; ++i) acc[i] += __shfl_xor(acc[i], m, 64);
    }

    if (g == 0) {
        #pragma unroll
        for (int i = 0; i < 8; ++i) {
            float v = acc[i] * di;           // deferred destination norm
            if (MODE == 0) v = di * fmaxf(v + bias[r * 8 + i], 0.0f);
            outp[(size_t)node * CH + r * 8 + i] = (unsigned short)bf16s(v);
        }
    }
}

// ---------------- final GEMM (MFMA): out = sigmoid(t @ W2^T + b2), fp32 ----------------

__global__ __launch_bounds__(256) void final_gemm(const unsigned short* __restrict__ t_,
                                                  const float* __restrict__ W2,
                                                  const float* __restrict__ b2,
                                                  float* __restrict__ out, int n) {
    __shared__ short w2s[48 * CH];   // [48][64] bf16 swizzled, row 47 zeroed (6 KB)
    int t = threadIdx.x;
    int row0 = blockIdx.x * 64;

    for (int i = t; i < 48 * (CH / 4); i += 256) {
        int row = i >> 4;
        int f4  = i & 15;
        float4 v;
        if (row < CO) v = *(const float4*)(W2 + (size_t)row * CH + f4 * 4);
        else          v = make_float4(0.f, 0.f, 0.f, 0.f);
        short4v b;
        b[0] = bf16s(v.x); b[1] = bf16s(v.y); b[2] = bf16s(v.z); b[3] = bf16s(v.w);
        int kbyte = f4 * 8;
        *(short4v*)((char*)w2s + (row << 7) + (kbyte ^ ((row & 7) << 4))) = b;
    }
    __syncthreads();

    int l  = t & 63;
    int w  = t >> 6;
    int g  = l >> 4;
    int lr = l & 15;

    bf16x8 bfr[3][2];
    #pragma unroll
    for (int cb = 0; cb < 3; ++cb) {
        int col = cb * 16 + lr;
        #pragma unroll
        for (int kk = 0; kk < 2; ++kk) {
            int kbyte = (kk * 32 + g * 8) * 2;
            bfr[cb][kk] = *(const bf16x8*)((char*)w2s + (col << 7) + (kbyte ^ ((col & 7) << 4)));
        }
    }

    f32x4 acc[3];
    #pragma unroll
    for (int cb = 0; cb < 3; ++cb) acc[cb] = (f32x4){0.f, 0.f, 0.f, 0.f};

    int arow = row0 + w * 16 + lr;
    if (arow >= n) arow = n - 1;
    const unsigned short* ga = t_ + (size_t)arow * CH + g * 8;

    #pragma unroll
    for (int kk = 0; kk < 2; ++kk) {
        bf16x8 af = *(const bf16x8*)(ga + kk * 32);
        #pragma unroll
        for (int cb = 0; cb < 3; ++cb)
            acc[cb] = __builtin_amdgcn_mfma_f32_16x16x32_bf16(af, bfr[cb][kk], acc[cb], 0, 0, 0);
    }

    #pragma unroll
    for (int cb = 0; cb < 3; ++cb) {
        #pragma unroll
        for (int r = 0; r < 4; ++r) {
            int drow = row0 + w * 16 + g * 4 + r;
            int col  = cb * 16 + lr;
            if (drow < n && col < CO) {
                float v = acc[cb][r] + b2[col];
                out[(size_t)drow * CO + col] = 1.0f / (1.0f + __expf(-v));
            }
        }
    }
}

// ---------------- launch ----------------

extern "C" void kernel_launch(void* const* d_in, const int* in_sizes, int n_in,
                              void* d_out, int out_size, void* d_ws, size_t ws_size,
                              hipStream_t stream) {
    const float* x  = (const float*)d_in[0];
    const int*   ei = (const int*)d_in[1];
    const float* W1 = (const float*)d_in[2];
    const float* b1 = (const float*)d_in[3];
    const float* W2 = (const float*)d_in[4];
    const float* b2 = (const float*)d_in[5];
    float* out = (float*)d_out;

    int n = in_sizes[0] / CIN;   // 100000
    int E = in_sizes[1] / 2;     // 1600000
    const int* src = ei;
    const int* dst = ei + E;

    // workspace layout (16B-aligned regions), total ~46.8 MB
    int*   cnt     = (int*)d_ws;                           // NPAD ints      (0.4 MB)
    float* dinv    = (float*)(cnt + NPAD);                 // NPAD floats    (0.4 MB)
    int*   bin_cnt = (int*)(dinv + NPAD);                  // 64*16 ints (padded 64B apart)
    int*   ell     = bin_cnt + 1024;                       // NPAD*48 ints   (19.7 MB)
    unsigned short* h1p   = (unsigned short*)(ell + (size_t)NPAD * ELLW); // NPAD*64 (13.1 MB)
    unsigned short* agg1p = h1p + (size_t)NPAD * CH;                      // NPAD*64 (13.1 MB)
    unsigned short* tbuf  = h1p;             // alias: h1p dead after aggregate<0>
    long long* bins = (long long*)h1p;       // alias: 13.6MB over h1p + head of agg1p,
                                             // dead before gemm1 writes h1p (serialized)

    int nb_n = (n + 255) / 256;
    int nb_w = (n + 3) / 4;                    // 4 waves/block, 1 node/wave
    int nb_g = (n + 63) / 64;
    int nchunks = (E + EDGE_CHUNK - 1) / EDGE_CHUNK;

    // ELL build: 64-way bin once, scatter sub-bin-by-sub-bin within-XCD
    zero_i32<<<nb_n, 256, 0, stream>>>(cnt, n);
    zero_i32<<<4, 256, 0, stream>>>(bin_cnt, 1024);
    bin_edges<<<nchunks, 256, 0, stream>>>(src, dst, bin_cnt, bins, E, 64.0f / (float)n);
    fill_ell2<<<2048, 256, 0, stream>>>(bins, bin_cnt, cnt, ell);
    dinv_k<<<nb_n, 256, 0, stream>>>(cnt, dinv, n);

    // layer 1: premultiplied gemm -> pure-add aggregate (relu+b1+premult fused)
    gemm1_mfma<<<nb_g, 256, 0, stream>>>(x, W1, dinv, h1p, n);
    aggregate<0><<<nb_w, 256, 0, stream>>>(h1p, dinv, ell, cnt, b1, agg1p, n);

    // layer 2: aggregate first (linearity), then W2 gemm fused with b2+sigmoid
    aggregate<1><<<nb_w, 256, 0, stream>>>(agg1p, dinv, ell, cnt, nullptr, tbuf, n);
    final_gemm<<<nb_g, 256, 0, stream>>>(tbuf, W2, b2, out, n);
}

// Round 11
// 178.638 us; speedup vs baseline: 1.4668x; 1.4668x over previous
//
#include <hip/hip_runtime.h>
#include <hip/hip_bf16.h>
#include <math.h>

#define CIN 256
#define CH  64
#define CO  47
#define NPAD 102400   // n=100000 rounded up
#define ELLW 48       // ELL width; deg ~ Poisson(16); overflow guarded
#define NPB 200       // nodes per bin (exact int binning: bin = d / NPB)
#define BINCAP 4096   // edges per bin cap: mean 3200, sigma 57 -> +15.8 sigma
#define EDGE_CHUNK 8192

typedef __attribute__((ext_vector_type(8))) short bf16x8;
typedef __attribute__((ext_vector_type(4))) short short4v;
typedef __attribute__((ext_vector_type(4))) float f32x4;

__device__ inline short bf16s(float f) {
    union { __hip_bfloat16 h; short s; } u;
    u.h = __float2bfloat16(f);
    return u.s;
}

__device__ inline float bf2f(short u) {
    union { unsigned int i; float f; } v;
    v.i = ((unsigned int)(unsigned short)u) << 16;
    return v.f;
}

// ---------------- binned ELL build, LDS-resident assembly ----------------
// r10 lesson: epoch-ordered global scatter starves parallelism (105us); r9
// lesson: unordered global scatter thrashes L2 (WRITE 64MB). Mechanism that
// works: assemble each ELL row COMPLETELY in LDS, write once, fully formed.
// Phase 1 bins edges by dst/200 (500 bins). Phase 2: one block per bin builds
// its 200-node sub-table (38.4KB LDS) with LDS atomics, then streams full
// 192B rows out coalesced. Global random scatter: eliminated.

__global__ void zero_i32(int* __restrict__ p, int n) {
    int i = blockIdx.x * blockDim.x + threadIdx.x;
    if (i < n) p[i] = 0;
}

__global__ __launch_bounds__(256) void bin_edges(const int* __restrict__ src,
                                                 const int* __restrict__ dst,
                                                 int* __restrict__ bin_cnt,
                                                 long long* __restrict__ bins,
                                                 int E, int nbins) {
    __shared__ int2 stage[EDGE_CHUNK];           // 64 KB
    __shared__ int lcnt[512], lbase[512], lcur[512], gbase[512];
    __shared__ int sa[512], sb_[512];
    int t = threadIdx.x;
    int base = blockIdx.x * EDGE_CHUNK;
    int end = min(base + EDGE_CHUNK, E);
    for (int i = t; i < 512; i += 256) lcnt[i] = 0;
    __syncthreads();

    // pass A: per-bin counts (exact: bin = d / NPB, same formula in phase 2)
    for (int i = base + t; i < end; i += 256) {
        int d = __builtin_nontemporal_load(&dst[i]);
        atomicAdd(&lcnt[d / NPB], 1);
    }
    __syncthreads();

    // parallel inclusive scan (Hillis-Steele, 512 wide, 9 steps)
    for (int i = t; i < 512; i += 256) sa[i] = lcnt[i];
    __syncthreads();
    int off = 1;
    #pragma unroll
    for (int s = 0; s < 9; ++s) {
        int* srcp = (s & 1) ? sb_ : sa;
        int* dstp = (s & 1) ? sa : sb_;
        for (int i = t; i < 512; i += 256)
            dstp[i] = srcp[i] + (i >= off ? srcp[i - off] : 0);
        __syncthreads();
        off <<= 1;
    }
    for (int i = t; i < 512; i += 256) {         // inclusive in sb_ (last dst)
        int excl = sb_[i] - lcnt[i];
        lbase[i] = excl;
        lcur[i] = excl;
    }
    __syncthreads();

    // pass B: stage grouped by bin
    for (int i = base + t; i < end; i += 256) {
        int d = __builtin_nontemporal_load(&dst[i]);
        int s = __builtin_nontemporal_load(&src[i]);
        int pos = atomicAdd(&lcur[d / NPB], 1);
        stage[pos] = make_int2(d, s);
    }
    __syncthreads();

    // reserve global space: one atomic per non-empty bin (counters 64B apart)
    for (int i = t; i < nbins; i += 256)
        gbase[i] = lcnt[i] ? atomicAdd(&bin_cnt[i << 4], lcnt[i]) : 0;
    __syncthreads();

    // pass C: copy out, coalesced within bin segments
    int total = end - base;
    for (int j = t; j < total; j += 256) {
        int2 e = stage[j];
        int b = e.x / NPB;
        int pos = gbase[b] + (j - lbase[b]);
        if (pos < BINCAP)
            bins[(size_t)b * BINCAP + pos] =
                ((long long)(unsigned)e.y << 32) | (unsigned)e.x;
    }
}

__global__ __launch_bounds__(256) void fill_ell3(const long long* __restrict__ bins,
                                                 const int* __restrict__ bin_cnt,
                                                 int* __restrict__ cnt,
                                                 float* __restrict__ dinv,
                                                 int* __restrict__ ell, int n) {
    __shared__ int lell[NPB * ELLW];             // 38.4 KB
    __shared__ int lcnt[NPB];
    int b = blockIdx.x;
    int node0 = b * NPB;
    int nn = min(NPB, n - node0);
    int t = threadIdx.x;
    if (t < NPB) lcnt[t] = 0;
    __syncthreads();

    int c_b = min(bin_cnt[b << 4], BINCAP);
    const long long* bb = bins + (size_t)b * BINCAP;
    for (int i = t; i < c_b; i += 256) {
        long long e = __builtin_nontemporal_load(&bb[i]);
        int d = (int)(e & 0xffffffffLL);
        int s = (int)(e >> 32);
        int slot = atomicAdd(&lcnt[d - node0], 1);   // LDS atomic
        if (slot < ELLW) lell[(d - node0) * ELLW + slot] = s;
    }
    __syncthreads();

    // stream out full rows (192B each, int4-coalesced); garbage tail slots
    // (>= lcnt) are never read by aggregate (deg-guarded)
    int4* gell = (int4*)(ell + (size_t)node0 * ELLW);
    const int4* lel4 = (const int4*)lell;
    int tot4 = nn * (ELLW / 4);
    for (int i = t; i < tot4; i += 256) gell[i] = lel4[i];
    if (t < nn) {
        int c = min(lcnt[t], ELLW);
        cnt[node0 + t] = c;
        dinv[node0 + t] = rsqrtf(1.0f + (float)lcnt[t]);  // true degree for norm
    }
}

// ---------------- layer-1 GEMM (MFMA): h1p = dinv * (x @ W1^T)  (bf16 out) ----------------
// Premultiplied by dinv[row] so aggregation is pure adds. r6-proven LDS staging.

__global__ __launch_bounds__(256) void gemm1_mfma(const float* __restrict__ x,
                                                  const float* __restrict__ W1,
                                                  const float* __restrict__ dinv,
                                                  unsigned short* __restrict__ h1p, int n) {
    __shared__ short w1s[CH * CIN];  // [64][256] bf16, swizzled rows (32 KB)
    int t = threadIdx.x;
    int row0 = blockIdx.x * 64;

    for (int i = t; i < CH * (CIN / 4); i += 256) {
        int row = i >> 6;
        int f4  = i & 63;
        float4 v = *(const float4*)(W1 + (size_t)row * CIN + f4 * 4);
        short4v b;
        b[0] = bf16s(v.x); b[1] = bf16s(v.y); b[2] = bf16s(v.z); b[3] = bf16s(v.w);
        int kbyte = f4 * 8;
        *(short4v*)((char*)w1s + (row << 9) + (kbyte ^ ((row & 7) << 4))) = b;
    }
    __syncthreads();

    int l  = t & 63;
    int w  = t >> 6;
    int g  = l >> 4;
    int lr = l & 15;

    bf16x8 bfr[4][8];
    #pragma unroll
    for (int cb = 0; cb < 4; ++cb) {
        int col = cb * 16 + lr;
        #pragma unroll
        for (int kk = 0; kk < 8; ++kk) {
            int kbyte = (kk * 32 + g * 8) * 2;
            bfr[cb][kk] = *(const bf16x8*)((char*)w1s + (col << 9) + (kbyte ^ ((col & 7) << 4)));
        }
    }

    f32x4 acc[4];
    #pragma unroll
    for (int cb = 0; cb < 4; ++cb) acc[cb] = (f32x4){0.f, 0.f, 0.f, 0.f};

    int arow = row0 + w * 16 + lr;
    if (arow >= n) arow = n - 1;     // clamp: loads stay in-bounds; store guarded
    const float* ga = x + (size_t)arow * CIN + g * 8;

    #pragma unroll
    for (int kk = 0; kk < 8; ++kk) {
        float4 a0 = *(const float4*)(ga + kk * 32);
        float4 a1 = *(const float4*)(ga + kk * 32 + 4);
        bf16x8 af;
        af[0] = bf16s(a0.x); af[1] = bf16s(a0.y); af[2] = bf16s(a0.z); af[3] = bf16s(a0.w);
        af[4] = bf16s(a1.x); af[5] = bf16s(a1.y); af[6] = bf16s(a1.z); af[7] = bf16s(a1.w);
        #pragma unroll
        for (int cb = 0; cb < 4; ++cb)
            acc[cb] = __builtin_amdgcn_mfma_f32_16x16x32_bf16(af, bfr[cb][kk], acc[cb], 0, 0, 0);
    }

    float dv[4];
    #pragma unroll
    for (int r = 0; r < 4; ++r) {
        int drow = row0 + w * 16 + g * 4 + r;
        dv[r] = dinv[drow < n ? drow : (n - 1)];
    }
    #pragma unroll
    for (int cb = 0; cb < 4; ++cb) {
        #pragma unroll
        for (int r = 0; r < 4; ++r) {
            int drow = row0 + w * 16 + g * 4 + r;   // C/D: col=lane&15, row=(lane>>4)*4+reg
            if (drow < n)
                h1p[(size_t)drow * CH + cb * 16 + lr] = (unsigned short)bf16s(acc[cb][r] * dv[r]);
        }
    }
}

// ---------------- gather aggregation over ELL: pure adds, 8-edge groups, x2 unroll ----
// MODE 0 (layer 1): out = bf16( di * relu(di*acc + b1) )   [premult for layer 2]
// MODE 1 (layer 2): out = bf16( di * acc )                  [input to final gemm]

template <int MODE>
__global__ __launch_bounds__(256) void aggregate(const unsigned short* __restrict__ h,
                                                 const float* __restrict__ dinv,
                                                 const int* __restrict__ ell,
                                                 const int* __restrict__ cnt,
                                                 const float* __restrict__ bias,
                                                 unsigned short* __restrict__ outp, int n) {
    int lane = threadIdx.x & 63;
    int node = blockIdx.x * (blockDim.x >> 6) + (threadIdx.x >> 6);
    if (node >= n) return;
    int g = lane >> 3;
    int r = lane & 7;

    float di = dinv[node];
    int deg = cnt[node];                     // already clamped to ELLW
    const int* row = ell + (size_t)node * ELLW;

    float acc[8];
    #pragma unroll
    for (int i = 0; i < 8; ++i) acc[i] = 0.f;

    if (g == 0) {                            // self term: h_p[node], weight 1
        bf16x8 v = *(const bf16x8*)(h + (size_t)node * CH + r * 8);
        #pragma unroll
        for (int i = 0; i < 8; ++i) acc[i] += bf2f(v[i]);
    }

    int j = g;
    for (; j + 8 < deg; j += 16) {           // x2 unroll: 2 rows in flight per lane
        int s0 = row[j];
        int s1 = row[j + 8];
        bf16x8 v0 = *(const bf16x8*)(h + (size_t)s0 * CH + r * 8);
        bf16x8 v1 = *(const bf16x8*)(h + (size_t)s1 * CH + r * 8);
        #pragma unroll
        for (int i = 0; i < 8; ++i) acc[i] += bf2f(v0[i]) + bf2f(v1[i]);
    }
    if (j < deg) {
        int s = row[j];
        bf16x8 v = *(const bf16x8*)(h + (size_t)s * CH + r * 8);
        #pragma unroll
        for (int i = 0; i < 8; ++i) acc[i] += bf2f(v[i]);
    }

    #pragma unroll
    for (int m = 8; m <= 32; m <<= 1) {
        #pragma unroll
        for (int i = 0; i < 8; ++i) acc[i] += __shfl_xor(acc[i], m, 64);
    }

    if (g == 0) {
        #pragma unroll
        for (int i = 0; i < 8; ++i) {
            float v = acc[i] * di;           // deferred destination norm
            if (MODE == 0) v = di * fmaxf(v + bias[r * 8 + i], 0.0f);
            outp[(size_t)node * CH + r * 8 + i] = (unsigned short)bf16s(v);
        }
    }
}

// ---------------- final GEMM (MFMA): out = sigmoid(t @ W2^T + b2), fp32 ----------------

__global__ __launch_bounds__(256) void final_gemm(const unsigned short* __restrict__ t_,
                                                  const float* __restrict__ W2,
                                                  const float* __restrict__ b2,
                                                  float* __restrict__ out, int n) {
    __shared__ short w2s[48 * CH];   // [48][64] bf16 swizzled, row 47 zeroed (6 KB)
    int t = threadIdx.x;
    int row0 = blockIdx.x * 64;

    for (int i = t; i < 48 * (CH / 4); i += 256) {
        int row = i >> 4;
        int f4  = i & 15;
        float4 v;
        if (row < CO) v = *(const float4*)(W2 + (size_t)row * CH + f4 * 4);
        else          v = make_float4(0.f, 0.f, 0.f, 0.f);
        short4v b;
        b[0] = bf16s(v.x); b[1] = bf16s(v.y); b[2] = bf16s(v.z); b[3] = bf16s(v.w);
        int kbyte = f4 * 8;
        *(short4v*)((char*)w2s + (row << 7) + (kbyte ^ ((row & 7) << 4))) = b;
    }
    __syncthreads();

    int l  = t & 63;
    int w  = t >> 6;
    int g  = l >> 4;
    int lr = l & 15;

    bf16x8 bfr[3][2];
    #pragma unroll
    for (int cb = 0; cb < 3; ++cb) {
        int col = cb * 16 + lr;
        #pragma unroll
        for (int kk = 0; kk < 2; ++kk) {
            int kbyte = (kk * 32 + g * 8) * 2;
            bfr[cb][kk] = *(const bf16x8*)((char*)w2s + (col << 7) + (kbyte ^ ((col & 7) << 4)));
        }
    }

    f32x4 acc[3];
    #pragma unroll
    for (int cb = 0; cb < 3; ++cb) acc[cb] = (f32x4){0.f, 0.f, 0.f, 0.f};

    int arow = row0 + w * 16 + lr;
    if (arow >= n) arow = n - 1;
    const unsigned short* ga = t_ + (size_t)arow * CH + g * 8;

    #pragma unroll
    for (int kk = 0; kk < 2; ++kk) {
        bf16x8 af = *(const bf16x8*)(ga + kk * 32);
        #pragma unroll
        for (int cb = 0; cb < 3; ++cb)
            acc[cb] = __builtin_amdgcn_mfma_f32_16x16x32_bf16(af, bfr[cb][kk], acc[cb], 0, 0, 0);
    }

    #pragma unroll
    for (int cb = 0; cb < 3; ++cb) {
        #pragma unroll
        for (int r = 0; r < 4; ++r) {
            int drow = row0 + w * 16 + g * 4 + r;
            int col  = cb * 16 + lr;
            if (drow < n && col < CO) {
                float v = acc[cb][r] + b2[col];
                out[(size_t)drow * CO + col] = 1.0f / (1.0f + __expf(-v));
            }
        }
    }
}

// ---------------- launch ----------------

extern "C" void kernel_launch(void* const* d_in, const int* in_sizes, int n_in,
                              void* d_out, int out_size, void* d_ws, size_t ws_size,
                              hipStream_t stream) {
    const float* x  = (const float*)d_in[0];
    const int*   ei = (const int*)d_in[1];
    const float* W1 = (const float*)d_in[2];
    const float* b1 = (const float*)d_in[3];
    const float* W2 = (const float*)d_in[4];
    const float* b2 = (const float*)d_in[5];
    float* out = (float*)d_out;

    int n = in_sizes[0] / CIN;   // 100000
    int E = in_sizes[1] / 2;     // 1600000
    const int* src = ei;
    const int* dst = ei + E;

    // workspace layout (16B-aligned regions), total ~46.8 MB
    int*   cnt     = (int*)d_ws;                           // NPAD ints      (0.4 MB)
    float* dinv    = (float*)(cnt + NPAD);                 // NPAD floats    (0.4 MB)
    int*   bin_cnt = (int*)(dinv + NPAD);                  // 512*16 ints (64B apart, 32KB)
    int*   ell     = bin_cnt + 8192;                       // NPAD*48 ints   (19.7 MB)
    unsigned short* h1p   = (unsigned short*)(ell + (size_t)NPAD * ELLW); // NPAD*64 (13.1 MB)
    unsigned short* agg1p = h1p + (size_t)NPAD * CH;                      // NPAD*64 (13.1 MB)
    unsigned short* tbuf  = h1p;             // alias: h1p dead after aggregate<0>
    long long* bins = (long long*)h1p;       // alias: 500*4096*8B = 16.4MB over h1p +
                                             // head of agg1p; dead before gemm1 writes h1p

    int nb_n = (n + 255) / 256;
    int nb_w = (n + 3) / 4;                    // 4 waves/block, 1 node/wave
    int nb_g = (n + 63) / 64;
    int nbins = (n + NPB - 1) / NPB;           // 500
    int nchunks = (E + EDGE_CHUNK - 1) / EDGE_CHUNK;  // 196

    // ELL build: bin by dst/200, then LDS-resident row assembly (write-once)
    zero_i32<<<32, 256, 0, stream>>>(bin_cnt, 8192);
    bin_edges<<<nchunks, 256, 0, stream>>>(src, dst, bin_cnt, bins, E, nbins);
    fill_ell3<<<nbins, 256, 0, stream>>>(bins, bin_cnt, cnt, dinv, ell, n);

    // layer 1: premultiplied gemm -> pure-add aggregate (relu+b1+premult fused)
    gemm1_mfma<<<nb_g, 256, 0, stream>>>(x, W1, dinv, h1p, n);
    aggregate<0><<<nb_w, 256, 0, stream>>>(h1p, dinv, ell, cnt, b1, agg1p, n);

    // layer 2: aggregate first (linearity), then W2 gemm fused with b2+sigmoid
    aggregate<1><<<nb_w, 256, 0, stream>>>(agg1p, dinv, ell, cnt, nullptr, tbuf, n);
    final_gemm<<<nb_g, 256, 0, stream>>>(tbuf, W2, b2, out, n);
}